// Round 1
// baseline (1038.009 us; speedup 1.0000x reference)
//
#include <hip/hip_runtime.h>
#include <hip/hip_bf16.h>

// Model_39676907885326: out = softmax(causal(q)) @ e
//   e[i,j,l]  = sum_k in[i,j,k] * w[l,k,j]
//   q[i,j,l]  = (sum_k in[i,j,k]) * w[i,j,l] / (0.5 + sum_l w[i,j,l])
//   attn      = softmax_l<=j(q)
//   out[i]    = attn[i] @ e[i]
//
// Workspace layout (REQUIRES ws_size >= 2 * N^3 * 2 bytes = 226,492,416):
//   R0 [0 .. N3)  bf16 : wt[j][l][k] (kT output, consumed by k_e_gemm),
//                        then REUSED for attn[i][j][m] (k_attn runs after
//                        k_e_gemm in stream order).
//   R1 [N3 .. 2*N3) bf16 : e[i][m][l]

#define N 384
#define N2 (N * N)
static const size_t N3 = (size_t)N * N * N;

__device__ __forceinline__ unsigned short f32_to_bf16(float f) {
    unsigned int u = __float_as_uint(f);
    u += 0x7FFFu + ((u >> 16) & 1u);   // round-to-nearest-even
    return (unsigned short)(u >> 16);
}
__device__ __forceinline__ float bf16_to_f32(unsigned short h) {
    return __uint_as_float((unsigned int)h << 16);
}

// ---------------------------------------------------------------------------
// kT: wt[j*N2 + l*N + k] = bf16(w[l*N2 + k*N + j])
// Equivalent to 2D transpose of M[r][j], r = l*N+k  (147456 x 384, f32->bf16)
// ---------------------------------------------------------------------------
__global__ __launch_bounds__(256) void kT(const float* __restrict__ w,
                                          unsigned short* __restrict__ wt) {
    __shared__ unsigned short tile[32][33];
    const int r0 = blockIdx.x * 32;
    const int j0 = blockIdx.y * 32;
    const int tx = threadIdx.x;          // 0..31
    const int ty = threadIdx.y;          // 0..7
#pragma unroll
    for (int yy = 0; yy < 32; yy += 8) {
        // coalesced read along j (stride-1 in source)
        tile[ty + yy][tx] = f32_to_bf16(w[(size_t)(r0 + ty + yy) * N + j0 + tx]);
    }
    __syncthreads();
#pragma unroll
    for (int yy = 0; yy < 32; yy += 8) {
        // coalesced write along r (stride-1 in dest)
        wt[(size_t)(j0 + ty + yy) * N2 + r0 + tx] = tile[tx][ty + yy];
    }
}

// ---------------------------------------------------------------------------
// k_e_gemm: for each j:  e[i, j, l] = sum_k in[i,j,k] * wt[j][l][k]
// 64x64 tile per block, 256 threads, 4x4 microtile, BK=16, fp32 accum.
// ---------------------------------------------------------------------------
__global__ __launch_bounds__(256) void k_e_gemm(const float* __restrict__ in,
                                                const unsigned short* __restrict__ wt,
                                                unsigned short* __restrict__ e) {
    __shared__ float As[16][68];   // [k][i] , pad 68 -> 16B-aligned rows, few conflicts
    __shared__ float Bs[16][68];   // [k][l]
    const int i0 = blockIdx.x * 64;
    const int l0 = blockIdx.y * 64;
    const int j  = blockIdx.z;
    const int t  = threadIdx.x;
    const int tx = t & 15, ty = t >> 4;       // 16x16 compute layout
    const int sr = t >> 2, sq = (t & 3) * 4;  // staging: row 0..63, k-quad

    const float*          Ap = in + (size_t)(i0 + sr) * N2 + (size_t)j * N + sq;
    const unsigned short* Bp = wt + (size_t)j * N2 + (size_t)(l0 + sr) * N + sq;

    float acc[4][4] = {};
    for (int k0 = 0; k0 < N; k0 += 16) {
        const float4  av = *(const float4*)(Ap + k0);
        const ushort4 bv = *(const ushort4*)(Bp + k0);
        __syncthreads();
        As[sq + 0][sr] = av.x;
        As[sq + 1][sr] = av.y;
        As[sq + 2][sr] = av.z;
        As[sq + 3][sr] = av.w;
        Bs[sq + 0][sr] = bf16_to_f32(bv.x);
        Bs[sq + 1][sr] = bf16_to_f32(bv.y);
        Bs[sq + 2][sr] = bf16_to_f32(bv.z);
        Bs[sq + 3][sr] = bf16_to_f32(bv.w);
        __syncthreads();
#pragma unroll
        for (int kk = 0; kk < 16; ++kk) {
            const float4 a = *(const float4*)&As[kk][ty * 4];
            const float4 b = *(const float4*)&Bs[kk][tx * 4];
            const float ar[4] = {a.x, a.y, a.z, a.w};
            const float br[4] = {b.x, b.y, b.z, b.w};
#pragma unroll
            for (int r = 0; r < 4; ++r)
#pragma unroll
                for (int c = 0; c < 4; ++c)
                    acc[r][c] = fmaf(ar[r], br[c], acc[r][c]);
        }
    }
#pragma unroll
    for (int r = 0; r < 4; ++r) {
        ushort4 o;
        o.x = f32_to_bf16(acc[r][0]);
        o.y = f32_to_bf16(acc[r][1]);
        o.z = f32_to_bf16(acc[r][2]);
        o.w = f32_to_bf16(acc[r][3]);
        *(ushort4*)(e + (size_t)(i0 + ty * 4 + r) * N2 + (size_t)j * N + l0 + tx * 4) = o;
    }
}

// ---------------------------------------------------------------------------
// k_attn: one wave per row (i,j). attn[i,j,l] = softmax_{l<=j}(scale * w[i,j,l])
//         scale = (sum_k in[i,j,k]) / (0.5 + sum_l w[i,j,l])
// ---------------------------------------------------------------------------
__global__ __launch_bounds__(256) void k_attn(const float* __restrict__ in,
                                              const float* __restrict__ w,
                                              unsigned short* __restrict__ attn) {
    const int row  = blockIdx.x * 4 + (threadIdx.x >> 6);  // flat (i*N + j)
    const int lane = threadIdx.x & 63;
    const int jr   = row % N;   // j within batch

    const float* ip = in + (size_t)row * N;
    const float* wp = w + (size_t)row * N;

    float wv[6];
    float rs_in = 0.f, rs_w = 0.f;
#pragma unroll
    for (int c = 0; c < 6; ++c) {
        rs_in += ip[lane + 64 * c];
        wv[c] = wp[lane + 64 * c];
        rs_w += wv[c];
    }
#pragma unroll
    for (int s = 1; s < 64; s <<= 1) {
        rs_in += __shfl_xor(rs_in, s, 64);
        rs_w  += __shfl_xor(rs_w, s, 64);
    }
    const float scale = rs_in / (0.5f + rs_w);

    float q[6];
    float mx = -INFINITY;
#pragma unroll
    for (int c = 0; c < 6; ++c) {
        const int l = lane + 64 * c;
        q[c] = (l <= jr) ? scale * wv[c] : -INFINITY;
        mx = fmaxf(mx, q[c]);
    }
#pragma unroll
    for (int s = 1; s < 64; s <<= 1) mx = fmaxf(mx, __shfl_xor(mx, s, 64));

    float p[6];
    float sum = 0.f;
#pragma unroll
    for (int c = 0; c < 6; ++c) {
        const int l = lane + 64 * c;
        p[c] = (l <= jr) ? exp2f((q[c] - mx) * 1.44269504f) : 0.f;
        sum += p[c];
    }
#pragma unroll
    for (int s = 1; s < 64; s <<= 1) sum += __shfl_xor(sum, s, 64);
    const float inv = 1.f / sum;
#pragma unroll
    for (int c = 0; c < 6; ++c)
        attn[(size_t)row * N + lane + 64 * c] = f32_to_bf16(p[c] * inv);
}

// ---------------------------------------------------------------------------
// k_av_gemm: for each i:  out[i, j, l] = sum_{m<=j} attn[i,j,m] * e[i,m,l]
// Triangular: K-loop clipped to j0+64.
// ---------------------------------------------------------------------------
__global__ __launch_bounds__(256) void k_av_gemm(const unsigned short* __restrict__ attn,
                                                 const unsigned short* __restrict__ e,
                                                 float* __restrict__ out) {
    __shared__ float As[16][68];   // [m][j]
    __shared__ float Bs[16][68];   // [m][l]
    const int j0 = blockIdx.x * 64;
    const int l0 = blockIdx.y * 64;
    const int i  = blockIdx.z;
    const int kmax = j0 + 64;      // attn[j,m]=0 beyond j; block max j = j0+63
    const int t  = threadIdx.x;
    const int tx = t & 15, ty = t >> 4;
    const int sr = t >> 2, sq = (t & 3) * 4;        // A staging
    const int bkk = t >> 4, blq = (t & 15) * 4;     // B staging

    const unsigned short* Ap = attn + (size_t)i * N2 + (size_t)(j0 + sr) * N + sq;
    const unsigned short* Bp = e    + (size_t)i * N2 + (size_t)bkk * N + l0 + blq;

    float acc[4][4] = {};
    for (int k0 = 0; k0 < kmax; k0 += 16) {
        const ushort4 av = *(const ushort4*)(Ap + k0);
        const ushort4 bv = *(const ushort4*)(Bp + (size_t)k0 * N);
        __syncthreads();
        As[sq + 0][sr] = bf16_to_f32(av.x);
        As[sq + 1][sr] = bf16_to_f32(av.y);
        As[sq + 2][sr] = bf16_to_f32(av.z);
        As[sq + 3][sr] = bf16_to_f32(av.w);
        float4 bw;
        bw.x = bf16_to_f32(bv.x);
        bw.y = bf16_to_f32(bv.y);
        bw.z = bf16_to_f32(bv.z);
        bw.w = bf16_to_f32(bv.w);
        *(float4*)&Bs[bkk][blq] = bw;
        __syncthreads();
#pragma unroll
        for (int kk = 0; kk < 16; ++kk) {
            const float4 a = *(const float4*)&As[kk][ty * 4];
            const float4 b = *(const float4*)&Bs[kk][tx * 4];
            const float ar[4] = {a.x, a.y, a.z, a.w};
            const float br[4] = {b.x, b.y, b.z, b.w};
#pragma unroll
            for (int r = 0; r < 4; ++r)
#pragma unroll
                for (int c = 0; c < 4; ++c)
                    acc[r][c] = fmaf(ar[r], br[c], acc[r][c]);
        }
    }
#pragma unroll
    for (int r = 0; r < 4; ++r) {
        float4 o = {acc[r][0], acc[r][1], acc[r][2], acc[r][3]};
        *(float4*)(out + (size_t)i * N2 + (size_t)(j0 + ty * 4 + r) * N + l0 + tx * 4) = o;
    }
}

extern "C" void kernel_launch(void* const* d_in, const int* in_sizes, int n_in,
                              void* d_out, int out_size, void* d_ws, size_t ws_size,
                              hipStream_t stream) {
    const float* in = (const float*)d_in[0];
    const float* w  = (const float*)d_in[1];
    float* out      = (float*)d_out;

    unsigned short* r0 = (unsigned short*)d_ws;       // wt, then attn
    unsigned short* e  = (unsigned short*)d_ws + N3;  // e (bf16)

    // 1) wt[j][l][k] = bf16(w[l][k][j])
    kT<<<dim3(N2 / 32, N / 32), dim3(32, 8), 0, stream>>>(w, r0);
    // 2) e = in @ wt^T (batched over j), bf16 out
    k_e_gemm<<<dim3(6, 6, N), 256, 0, stream>>>(in, r0, e);
    // 3) attn (overwrites wt region — safe: stream-ordered after k_e_gemm)
    k_attn<<<dim3(N2 / 4), 256, 0, stream>>>(in, w, r0);
    // 4) out = attn @ e (batched over i), triangular K clip
    k_av_gemm<<<dim3(6, 6, N), 256, 0, stream>>>(r0, e, out);
}

// Round 2
// 819.494 us; speedup vs baseline: 1.2666x; 1.2666x over previous
//
#include <hip/hip_runtime.h>
#include <hip/hip_bf16.h>

// Model_39676907885326: out = softmax(causal(q)) @ e
//   e[i,j,l]  = sum_k in[i,j,k] * w[l,k,j]
//   q[i,j,l]  = (sum_k in[i,j,k]) * w[i,j,l] / (0.5 + sum_l w[i,j,l])
//   attn      = softmax_l<=j(q)
//   out[i]    = attn[i] @ e[i]
//
// Pipeline (ws = 2 regions of N^3 bf16 = 226,492,416 B total):
//   kT       : w -> wt[j][l][k]   (R0)
//   k_e_mfma : in, wt -> e[i][j][l]  (R1)   [MFMA bf16]
//   k_eT     : e -> et[i][l][m]   (R0, overwrites wt)
//   k_attn   : in, w -> attn      (R1, overwrites e)
//   k_av_mfma: attn, et -> out               [MFMA bf16, triangular]

#define N 384
#define N2 (N * N)
#define BM 128
#define BK 64
static const size_t N3 = (size_t)N * N * N;

typedef __attribute__((ext_vector_type(8))) short s16x8;
typedef __attribute__((ext_vector_type(4))) float f32x4;

__device__ __forceinline__ unsigned short f32_to_bf16(float f) {
    unsigned int u = __float_as_uint(f);
    u += 0x7FFFu + ((u >> 16) & 1u);   // round-to-nearest-even
    return (unsigned short)(u >> 16);
}
__device__ __forceinline__ float bf16_to_f32(unsigned short h) {
    return __uint_as_float((unsigned int)h << 16);
}
__device__ __forceinline__ unsigned int pk2(float a, float b) {
    return (unsigned int)f32_to_bf16(a) | ((unsigned int)f32_to_bf16(b) << 16);
}

// ---------------------------------------------------------------------------
// kT: wt[j*N2 + l*N + k] = bf16(w[l*N2 + k*N + j])  (2D transpose 147456x384)
// ---------------------------------------------------------------------------
__global__ __launch_bounds__(256) void kT(const float* __restrict__ w,
                                          unsigned short* __restrict__ wt) {
    __shared__ unsigned short tile[32][33];
    const int r0 = blockIdx.x * 32;
    const int j0 = blockIdx.y * 32;
    const int tx = threadIdx.x;
    const int ty = threadIdx.y;
#pragma unroll
    for (int yy = 0; yy < 32; yy += 8)
        tile[ty + yy][tx] = f32_to_bf16(w[(size_t)(r0 + ty + yy) * N + j0 + tx]);
    __syncthreads();
#pragma unroll
    for (int yy = 0; yy < 32; yy += 8)
        wt[(size_t)(j0 + ty + yy) * N2 + r0 + tx] = tile[tx][ty + yy];
}

// ---------------------------------------------------------------------------
// k_e_mfma: per j:  e[i, j, l] = sum_k in[i,j,k] * wt[j][l][k]
// 128x128 tile, BK=64, 4 waves (2x2 of 64x64), mfma_f32_16x16x32_bf16.
// LDS chunk-swizzle: LDS[row][c] holds source k-chunk (c ^ (row&7)), 8 bf16
// chunks; fragment reads apply the same XOR -> conflict-minimal ds_read_b128.
// ---------------------------------------------------------------------------
__global__ __launch_bounds__(256) void k_e_mfma(const float* __restrict__ in,
                                                const unsigned short* __restrict__ wt,
                                                unsigned short* __restrict__ e) {
    __shared__ __align__(16) unsigned short As[BM * BK];
    __shared__ __align__(16) unsigned short Bs[BM * BK];
    const int i0 = blockIdx.x * BM;
    const int l0 = blockIdx.y * BM;
    const int j  = blockIdx.z;
    const int t    = threadIdx.x;
    const int lane = t & 63;
    const int wv   = t >> 6;
    const int wr   = (wv >> 1) * 64;
    const int wc   = (wv & 1) * 64;
    // staging: thread t covers chunk indices CI = t*4+q -> row=t>>1, c=(t&1)*4+q
    const int srow  = t >> 1;
    const int cbase = (t & 1) * 4;

    const float*          Abase = in + (size_t)(i0 + srow) * N2 + (size_t)j * N;
    const unsigned short* Bbase = wt + (size_t)j * N2 + (size_t)(l0 + srow) * N;
    unsigned short* AsW = As + srow * BK + cbase * 8;
    unsigned short* BsW = Bs + srow * BK + cbase * 8;
    int sc[4];
#pragma unroll
    for (int q = 0; q < 4; ++q) sc[q] = ((cbase + q) ^ (srow & 7)) * 8;

    f32x4 acc[4][4];
#pragma unroll
    for (int m = 0; m < 4; ++m)
#pragma unroll
        for (int n = 0; n < 4; ++n) acc[m][n] = (f32x4){0.f, 0.f, 0.f, 0.f};

    float4 va[4][2];
    uint4  vb[4];
#pragma unroll
    for (int q = 0; q < 4; ++q) {
        va[q][0] = *(const float4*)(Abase + sc[q]);
        va[q][1] = *(const float4*)(Abase + sc[q] + 4);
        vb[q]    = *(const uint4*)(Bbase + sc[q]);
    }

    for (int k0 = 0; k0 < N; k0 += BK) {
        __syncthreads();
#pragma unroll
        for (int q = 0; q < 4; ++q) {
            uint4 ac;
            ac.x = pk2(va[q][0].x, va[q][0].y);
            ac.y = pk2(va[q][0].z, va[q][0].w);
            ac.z = pk2(va[q][1].x, va[q][1].y);
            ac.w = pk2(va[q][1].z, va[q][1].w);
            *(uint4*)(AsW + q * 8) = ac;
            *(uint4*)(BsW + q * 8) = vb[q];
        }
        __syncthreads();
        if (k0 + BK < N) {
            const int kn = k0 + BK;
#pragma unroll
            for (int q = 0; q < 4; ++q) {
                va[q][0] = *(const float4*)(Abase + kn + sc[q]);
                va[q][1] = *(const float4*)(Abase + kn + sc[q] + 4);
                vb[q]    = *(const uint4*)(Bbase + kn + sc[q]);
            }
        }
#pragma unroll
        for (int kk = 0; kk < 2; ++kk) {
            s16x8 af[4], bf[4];
#pragma unroll
            for (int m = 0; m < 4; ++m) {
                const int row = wr + m * 16 + (lane & 15);
                const int x   = (kk * 4 + (lane >> 4)) ^ (row & 7);
                af[m] = *(const s16x8*)(As + row * BK + x * 8);
            }
#pragma unroll
            for (int n = 0; n < 4; ++n) {
                const int row = wc + n * 16 + (lane & 15);
                const int x   = (kk * 4 + (lane >> 4)) ^ (row & 7);
                bf[n] = *(const s16x8*)(Bs + row * BK + x * 8);
            }
#pragma unroll
            for (int m = 0; m < 4; ++m)
#pragma unroll
                for (int n = 0; n < 4; ++n)
                    acc[m][n] = __builtin_amdgcn_mfma_f32_16x16x32_bf16(
                        af[m], bf[n], acc[m][n], 0, 0, 0);
        }
    }
    // epilogue: D layout col=lane&15, row=(lane>>4)*4+reg (guide-verified)
    const int cc = lane & 15, rq = (lane >> 4) * 4;
#pragma unroll
    for (int m = 0; m < 4; ++m)
#pragma unroll
        for (int n = 0; n < 4; ++n)
#pragma unroll
            for (int r = 0; r < 4; ++r) {
                const int row = i0 + wr + m * 16 + rq + r;
                const int col = l0 + wc + n * 16 + cc;
                e[(size_t)row * N2 + (size_t)j * N + col] = f32_to_bf16(acc[m][n][r]);
            }
}

// ---------------------------------------------------------------------------
// k_eT: et[i][l][m] = e[i][m][l]  (batched 384x384 bf16 transpose)
// ---------------------------------------------------------------------------
__global__ __launch_bounds__(256) void k_eT(const unsigned short* __restrict__ e,
                                            unsigned short* __restrict__ et) {
    __shared__ unsigned short tile[64][68];
    const int m0 = blockIdx.x * 64, l0 = blockIdx.y * 64;
    const size_t ib = (size_t)blockIdx.z * N2;
    const int t  = threadIdx.x;
    const int c4 = (t & 15) * 4, r = t >> 4;   // r 0..15
#pragma unroll
    for (int p = 0; p < 4; ++p) {
        ushort4 v = *(const ushort4*)(e + ib + (size_t)(m0 + r + 16 * p) * N + l0 + c4);
        tile[c4 + 0][r + 16 * p] = v.x;
        tile[c4 + 1][r + 16 * p] = v.y;
        tile[c4 + 2][r + 16 * p] = v.z;
        tile[c4 + 3][r + 16 * p] = v.w;
    }
    __syncthreads();
#pragma unroll
    for (int p = 0; p < 4; ++p) {
        const int lr = r + 16 * p;
        ushort4 v = *(const ushort4*)&tile[lr][c4];
        *(ushort4*)(et + ib + (size_t)(l0 + lr) * N + m0 + c4) = v;
    }
}

// ---------------------------------------------------------------------------
// k_attn: one wave per row (i,j). attn[i,j,l] = softmax_{l<=j}(scale * w[i,j,l])
// ---------------------------------------------------------------------------
__global__ __launch_bounds__(256) void k_attn(const float* __restrict__ in,
                                              const float* __restrict__ w,
                                              unsigned short* __restrict__ attn) {
    const int row  = blockIdx.x * 4 + (threadIdx.x >> 6);
    const int lane = threadIdx.x & 63;
    const int jr   = row % N;

    const float* ip = in + (size_t)row * N;
    const float* wp = w + (size_t)row * N;

    float wv[6];
    float rs_in = 0.f, rs_w = 0.f;
#pragma unroll
    for (int c = 0; c < 6; ++c) {
        rs_in += ip[lane + 64 * c];
        wv[c] = wp[lane + 64 * c];
        rs_w += wv[c];
    }
#pragma unroll
    for (int s = 1; s < 64; s <<= 1) {
        rs_in += __shfl_xor(rs_in, s, 64);
        rs_w  += __shfl_xor(rs_w, s, 64);
    }
    const float scale = rs_in / (0.5f + rs_w);

    float q[6];
    float mx = -INFINITY;
#pragma unroll
    for (int c = 0; c < 6; ++c) {
        const int l = lane + 64 * c;
        q[c] = (l <= jr) ? scale * wv[c] : -INFINITY;
        mx = fmaxf(mx, q[c]);
    }
#pragma unroll
    for (int s = 1; s < 64; s <<= 1) mx = fmaxf(mx, __shfl_xor(mx, s, 64));

    float p[6];
    float sum = 0.f;
#pragma unroll
    for (int c = 0; c < 6; ++c) {
        const int l = lane + 64 * c;
        p[c] = (l <= jr) ? exp2f((q[c] - mx) * 1.44269504f) : 0.f;
        sum += p[c];
    }
#pragma unroll
    for (int s = 1; s < 64; s <<= 1) sum += __shfl_xor(sum, s, 64);
    const float inv = 1.f / sum;
#pragma unroll
    for (int c = 0; c < 6; ++c)
        attn[(size_t)row * N + lane + 64 * c] = f32_to_bf16(p[c] * inv);
}

// ---------------------------------------------------------------------------
// k_av_mfma: per i: out[i,j,l] = sum_{m<j0+128} attn[i,j,m] * et[i][l][m]
// Same MFMA structure; both operands bf16 K-major; triangular K clip.
// ---------------------------------------------------------------------------
__global__ __launch_bounds__(256) void k_av_mfma(const unsigned short* __restrict__ attn,
                                                 const unsigned short* __restrict__ et,
                                                 float* __restrict__ out) {
    __shared__ __align__(16) unsigned short As[BM * BK];
    __shared__ __align__(16) unsigned short Bs[BM * BK];
    const int j0 = blockIdx.x * BM;
    const int l0 = blockIdx.y * BM;
    const int i  = blockIdx.z;
    const int t    = threadIdx.x;
    const int lane = t & 63;
    const int wv   = t >> 6;
    const int wr   = (wv >> 1) * 64;
    const int wc   = (wv & 1) * 64;
    const int srow  = t >> 1;
    const int cbase = (t & 1) * 4;

    const unsigned short* Abase = attn + (size_t)i * N2 + (size_t)(j0 + srow) * N;
    const unsigned short* Bbase = et + (size_t)i * N2 + (size_t)(l0 + srow) * N;
    unsigned short* AsW = As + srow * BK + cbase * 8;
    unsigned short* BsW = Bs + srow * BK + cbase * 8;
    int sc[4];
#pragma unroll
    for (int q = 0; q < 4; ++q) sc[q] = ((cbase + q) ^ (srow & 7)) * 8;

    const int kmax = j0 + BM;   // attn[j,m]==0 for m>j; block rows j < j0+128

    f32x4 acc[4][4];
#pragma unroll
    for (int m = 0; m < 4; ++m)
#pragma unroll
        for (int n = 0; n < 4; ++n) acc[m][n] = (f32x4){0.f, 0.f, 0.f, 0.f};

    uint4 va[4], vb[4];
#pragma unroll
    for (int q = 0; q < 4; ++q) {
        va[q] = *(const uint4*)(Abase + sc[q]);
        vb[q] = *(const uint4*)(Bbase + sc[q]);
    }

    for (int k0 = 0; k0 < kmax; k0 += BK) {
        __syncthreads();
#pragma unroll
        for (int q = 0; q < 4; ++q) {
            *(uint4*)(AsW + q * 8) = va[q];
            *(uint4*)(BsW + q * 8) = vb[q];
        }
        __syncthreads();
        if (k0 + BK < kmax) {
            const int kn = k0 + BK;
#pragma unroll
            for (int q = 0; q < 4; ++q) {
                va[q] = *(const uint4*)(Abase + kn + sc[q]);
                vb[q] = *(const uint4*)(Bbase + kn + sc[q]);
            }
        }
#pragma unroll
        for (int kk = 0; kk < 2; ++kk) {
            s16x8 af[4], bf[4];
#pragma unroll
            for (int m = 0; m < 4; ++m) {
                const int row = wr + m * 16 + (lane & 15);
                const int x   = (kk * 4 + (lane >> 4)) ^ (row & 7);
                af[m] = *(const s16x8*)(As + row * BK + x * 8);
            }
#pragma unroll
            for (int n = 0; n < 4; ++n) {
                const int row = wc + n * 16 + (lane & 15);
                const int x   = (kk * 4 + (lane >> 4)) ^ (row & 7);
                bf[n] = *(const s16x8*)(Bs + row * BK + x * 8);
            }
#pragma unroll
            for (int m = 0; m < 4; ++m)
#pragma unroll
                for (int n = 0; n < 4; ++n)
                    acc[m][n] = __builtin_amdgcn_mfma_f32_16x16x32_bf16(
                        af[m], bf[n], acc[m][n], 0, 0, 0);
        }
    }
    const int cc = lane & 15, rq = (lane >> 4) * 4;
    float* obase = out + (size_t)i * N2;
#pragma unroll
    for (int m = 0; m < 4; ++m)
#pragma unroll
        for (int n = 0; n < 4; ++n)
#pragma unroll
            for (int r = 0; r < 4; ++r) {
                const int row = j0 + wr + m * 16 + rq + r;
                const int col = l0 + wc + n * 16 + cc;
                obase[(size_t)row * N + col] = acc[m][n][r];
            }
}

extern "C" void kernel_launch(void* const* d_in, const int* in_sizes, int n_in,
                              void* d_out, int out_size, void* d_ws, size_t ws_size,
                              hipStream_t stream) {
    const float* in = (const float*)d_in[0];
    const float* w  = (const float*)d_in[1];
    float* out      = (float*)d_out;

    unsigned short* r0 = (unsigned short*)d_ws;       // wt -> et
    unsigned short* r1 = (unsigned short*)d_ws + N3;  // e  -> attn

    kT<<<dim3(N2 / 32, N / 32), dim3(32, 8), 0, stream>>>(w, r0);
    k_e_mfma<<<dim3(3, 3, N), 256, 0, stream>>>(in, r0, r1);
    k_eT<<<dim3(6, 6, N), 256, 0, stream>>>(r1, r0);
    k_attn<<<dim3(N2 / 4), 256, 0, stream>>>(in, w, r1);
    k_av_mfma<<<dim3(3, 3, N), 256, 0, stream>>>(r1, r0, out);
}

// Round 3
// 660.277 us; speedup vs baseline: 1.5721x; 1.2411x over previous
//
#include <hip/hip_runtime.h>
#include <hip/hip_bf16.h>

// Model_39676907885326: out = softmax(causal(q)) @ e
//   e[i,j,l]  = sum_k in[i,j,k] * w[l,k,j]
//   attn[i,j,l] = softmax_{l<=j}( (sum_k in[i,j,k]) * w[i,j,l] / (0.5 + sum_l w[i,j,l]) )
//   out[i]    = attn[i] @ e[i]
//
// Pipeline (ws = 2 regions of N^3 bf16 = 226,492,416 B):
//   kT    : w -> wt[j][l][k]          (R0)
//   k_e2  : in, wt -> e[i][j][l]      (R1)  [MFMA, 128x384 tile, LDS epilogue]
//   k_eT  : e -> et[i][l][m]          (R0)
//   k_attn: in, w -> attn             (R1)
//   k_av2 : attn, et -> out                 [MFMA, triangular, LDS epilogue]

#define N 384
#define N2 (N * N)
#define BK 64
static const size_t N3 = (size_t)N * N * N;

typedef __attribute__((ext_vector_type(8))) short s16x8;
typedef __attribute__((ext_vector_type(4))) float f32x4;

__device__ __forceinline__ unsigned short f32_to_bf16(float f) {
    unsigned int u = __float_as_uint(f);
    u += 0x7FFFu + ((u >> 16) & 1u);
    return (unsigned short)(u >> 16);
}
__device__ __forceinline__ float bf16_to_f32(unsigned short h) {
    return __uint_as_float((unsigned int)h << 16);
}
__device__ __forceinline__ unsigned int pk2(float a, float b) {
    return (unsigned int)f32_to_bf16(a) | ((unsigned int)f32_to_bf16(b) << 16);
}

// ---------------------------------------------------------------------------
// kT: wt[j*N2 + r] = bf16(w[r*N + j]), r = l*N+k.  64x64 tiles: reads 256B/row,
// writes 128B/row (full cache lines).
// ---------------------------------------------------------------------------
__global__ __launch_bounds__(256) void kT(const float* __restrict__ w,
                                          unsigned short* __restrict__ wt) {
    __shared__ unsigned short tile[64][68];
    const int r0 = blockIdx.x * 64;
    const int j0 = blockIdx.y * 64;
    const int tx = threadIdx.x & 63;
    const int ty = threadIdx.x >> 6;   // 0..3
#pragma unroll
    for (int p = 0; p < 16; ++p) {
        const int r = ty * 16 + p;
        tile[r][tx] = f32_to_bf16(w[(size_t)(r0 + r) * N + j0 + tx]);
    }
    __syncthreads();
#pragma unroll
    for (int p = 0; p < 16; ++p) {
        const int jj = ty * 16 + p;
        wt[(size_t)(j0 + jj) * N2 + r0 + tx] = tile[tx][jj];
    }
}

// ---------------------------------------------------------------------------
// k_e2: per j: e[i0+0..127, j, 0..383] = in[i,j,:] . wt[j][l][:]
// 512 threads (8 waves, 2M x 4N), BM=128, BN=384, BK=64.
// Scheme (b) swizzle: linear source reads, XOR-swizzled LDS writes+reads.
// ---------------------------------------------------------------------------
__global__ __launch_bounds__(512) void k_e2(const float* __restrict__ in,
                                            const unsigned short* __restrict__ wt,
                                            unsigned short* __restrict__ e) {
    __shared__ __align__(16) unsigned char smem[65536];
    unsigned short* As = (unsigned short*)smem;            // [128][64]
    unsigned short* Bs = (unsigned short*)(smem + 16384);  // [384][64]

    const int lin = blockIdx.x;                 // 1152 = 8 * 144
    const int swz = (lin & 7) * 144 + (lin >> 3);
    const int i0 = (swz % 3) * 128;
    const int j  = swz / 3;

    const int t    = threadIdx.x;
    const int lane = t & 63;
    const int wv   = t >> 6;
    const int wr   = (wv >> 2) * 64;     // 0 / 64
    const int wc   = (wv & 3) * 96;      // 0 / 96 / 192 / 288
    const int fr   = lane & 15;
    const int fx   = lane >> 4;          // 0..3

    // A staging: 128 rows x 8 chunks(8 bf16); thread: row=t>>2, chunks (t&3)*2, +1
    const int sra = t >> 2;
    const int ca0 = (t & 3) * 2;
    const float* Ab = in + (size_t)(i0 + sra) * N2 + (size_t)j * N + ca0 * 8;
    unsigned short* AsW0 = As + sra * 64 + (((ca0 + 0) ^ (sra & 7)) * 8);
    unsigned short* AsW1 = As + sra * 64 + (((ca0 + 1) ^ (sra & 7)) * 8);

    // B staging: 384 rows x 8 chunks; thread covers (it*64 + (t>>3), t&7), it 0..5
    const int rb0 = t >> 3;
    const int cb  = t & 7;
    const unsigned short* Bb = wt + (size_t)j * N2 + (size_t)rb0 * N + cb * 8;
    unsigned short* BsW = Bs + rb0 * 64 + ((cb ^ (rb0 & 7)) * 8);

    f32x4 acc[4][6];
#pragma unroll
    for (int m = 0; m < 4; ++m)
#pragma unroll
        for (int n = 0; n < 6; ++n) acc[m][n] = (f32x4){0.f, 0.f, 0.f, 0.f};

    float4 va[4];
    uint4  vb[6];
#pragma unroll
    for (int f = 0; f < 4; ++f) va[f] = *(const float4*)(Ab + 4 * f);
#pragma unroll
    for (int it = 0; it < 6; ++it) vb[it] = *(const uint4*)(Bb + (size_t)it * 64 * N);

    for (int k0 = 0; k0 < N; k0 += BK) {
        __syncthreads();
        {
            uint4 a0, a1;
            a0.x = pk2(va[0].x, va[0].y); a0.y = pk2(va[0].z, va[0].w);
            a0.z = pk2(va[1].x, va[1].y); a0.w = pk2(va[1].z, va[1].w);
            a1.x = pk2(va[2].x, va[2].y); a1.y = pk2(va[2].z, va[2].w);
            a1.z = pk2(va[3].x, va[3].y); a1.w = pk2(va[3].z, va[3].w);
            *(uint4*)AsW0 = a0;
            *(uint4*)AsW1 = a1;
#pragma unroll
            for (int it = 0; it < 6; ++it) *(uint4*)(BsW + it * 64 * 64) = vb[it];
        }
        __syncthreads();
        if (k0 + BK < N) {
            const int kn = k0 + BK;
#pragma unroll
            for (int f = 0; f < 4; ++f) va[f] = *(const float4*)(Ab + kn + 4 * f);
#pragma unroll
            for (int it = 0; it < 6; ++it)
                vb[it] = *(const uint4*)(Bb + (size_t)it * 64 * N + kn);
        }
#pragma unroll
        for (int kk = 0; kk < 2; ++kk) {
            s16x8 af[4], bf[6];
#pragma unroll
            for (int m = 0; m < 4; ++m) {
                const int row = wr + m * 16 + fr;
                const int x   = (kk * 4 + fx) ^ (row & 7);
                af[m] = *(const s16x8*)(As + row * 64 + x * 8);
            }
#pragma unroll
            for (int n = 0; n < 6; ++n) {
                const int row = wc + n * 16 + fr;
                const int x   = (kk * 4 + fx) ^ (row & 7);
                bf[n] = *(const s16x8*)(Bs + row * 64 + x * 8);
            }
#pragma unroll
            for (int m = 0; m < 4; ++m)
#pragma unroll
                for (int n = 0; n < 6; ++n)
                    acc[m][n] = __builtin_amdgcn_mfma_f32_16x16x32_bf16(
                        af[m], bf[n], acc[m][n], 0, 0, 0);
        }
    }

    // Epilogue: assemble 64x384 bf16 halves in LDS, stream out full lines.
    const int rq = fx * 4;
    unsigned short* Cl = (unsigned short*)smem;   // [64][392]
#pragma unroll
    for (int h = 0; h < 2; ++h) {
        __syncthreads();
        if ((wv >> 2) == h) {
#pragma unroll
            for (int m = 0; m < 4; ++m)
#pragma unroll
                for (int n = 0; n < 6; ++n)
#pragma unroll
                    for (int r = 0; r < 4; ++r)
                        Cl[(m * 16 + rq + r) * 392 + wc + n * 16 + fr] =
                            f32_to_bf16(acc[m][n][r]);
        }
        __syncthreads();
#pragma unroll
        for (int it = 0; it < 6; ++it) {
            const int cid = it * 512 + t;
            const int row = cid / 48;
            const int c   = cid % 48;
            uint4 v = *(const uint4*)(Cl + row * 392 + c * 8);
            *(uint4*)(e + (size_t)(i0 + h * 64 + row) * N2 + (size_t)j * N + c * 8) = v;
        }
    }
}

// ---------------------------------------------------------------------------
// k_eT: et[i][l][m] = e[i][m][l]  (batched 384x384 bf16 transpose)
// ---------------------------------------------------------------------------
__global__ __launch_bounds__(256) void k_eT(const unsigned short* __restrict__ e,
                                            unsigned short* __restrict__ et) {
    __shared__ unsigned short tile[64][68];
    const int m0 = blockIdx.x * 64, l0 = blockIdx.y * 64;
    const size_t ib = (size_t)blockIdx.z * N2;
    const int t  = threadIdx.x;
    const int c4 = (t & 15) * 4, r = t >> 4;
#pragma unroll
    for (int p = 0; p < 4; ++p) {
        ushort4 v = *(const ushort4*)(e + ib + (size_t)(m0 + r + 16 * p) * N + l0 + c4);
        tile[c4 + 0][r + 16 * p] = v.x;
        tile[c4 + 1][r + 16 * p] = v.y;
        tile[c4 + 2][r + 16 * p] = v.z;
        tile[c4 + 3][r + 16 * p] = v.w;
    }
    __syncthreads();
#pragma unroll
    for (int p = 0; p < 4; ++p) {
        const int lr = r + 16 * p;
        ushort4 v = *(const ushort4*)&tile[lr][c4];
        *(ushort4*)(et + ib + (size_t)(l0 + lr) * N + m0 + c4) = v;
    }
}

// ---------------------------------------------------------------------------
// k_attn: one wave per row (i,j)
// ---------------------------------------------------------------------------
__global__ __launch_bounds__(256) void k_attn(const float* __restrict__ in,
                                              const float* __restrict__ w,
                                              unsigned short* __restrict__ attn) {
    const int row  = blockIdx.x * 4 + (threadIdx.x >> 6);
    const int lane = threadIdx.x & 63;
    const int jr   = row % N;

    const float* ip = in + (size_t)row * N;
    const float* wp = w + (size_t)row * N;

    float wv[6];
    float rs_in = 0.f, rs_w = 0.f;
#pragma unroll
    for (int c = 0; c < 6; ++c) {
        rs_in += ip[lane + 64 * c];
        wv[c] = wp[lane + 64 * c];
        rs_w += wv[c];
    }
#pragma unroll
    for (int s = 1; s < 64; s <<= 1) {
        rs_in += __shfl_xor(rs_in, s, 64);
        rs_w  += __shfl_xor(rs_w, s, 64);
    }
    const float scale = rs_in / (0.5f + rs_w);

    float q[6];
    float mx = -INFINITY;
#pragma unroll
    for (int c = 0; c < 6; ++c) {
        const int l = lane + 64 * c;
        q[c] = (l <= jr) ? scale * wv[c] : -INFINITY;
        mx = fmaxf(mx, q[c]);
    }
#pragma unroll
    for (int s = 1; s < 64; s <<= 1) mx = fmaxf(mx, __shfl_xor(mx, s, 64));

    float p[6];
    float sum = 0.f;
#pragma unroll
    for (int c = 0; c < 6; ++c) {
        const int l = lane + 64 * c;
        p[c] = (l <= jr) ? exp2f((q[c] - mx) * 1.44269504f) : 0.f;
        sum += p[c];
    }
#pragma unroll
    for (int s = 1; s < 64; s <<= 1) sum += __shfl_xor(sum, s, 64);
    const float inv = 1.f / sum;
#pragma unroll
    for (int c = 0; c < 6; ++c)
        attn[(size_t)row * N + lane + 64 * c] = f32_to_bf16(p[c] * inv);
}

// ---------------------------------------------------------------------------
// k_av2: per i: out[j0..j0+127, 0..383] = attn[i] @ e[i], K clipped to j0+128.
// Same structure as k_e2; A already bf16; fp32 out via 4-phase LDS epilogue.
// ---------------------------------------------------------------------------
__global__ __launch_bounds__(512) void k_av2(const unsigned short* __restrict__ attn,
                                             const unsigned short* __restrict__ et,
                                             float* __restrict__ out) {
    __shared__ __align__(16) unsigned char smem[65536];
    unsigned short* As = (unsigned short*)smem;            // [128][64]
    unsigned short* Bs = (unsigned short*)(smem + 16384);  // [384][64]

    const int lin = blockIdx.x;
    const int swz = (lin & 7) * 144 + (lin >> 3);
    const int j0 = (swz % 3) * 128;
    const int i  = swz / 3;
    const int kmax = j0 + 128;

    const int t    = threadIdx.x;
    const int lane = t & 63;
    const int wv   = t >> 6;
    const int wr   = (wv >> 2) * 64;
    const int wc   = (wv & 3) * 96;
    const int fr   = lane & 15;
    const int fx   = lane >> 4;

    const int sra = t >> 2;
    const int ca0 = (t & 3) * 2;
    const unsigned short* Ab = attn + (size_t)i * N2 + (size_t)(j0 + sra) * N + ca0 * 8;
    unsigned short* AsW0 = As + sra * 64 + (((ca0 + 0) ^ (sra & 7)) * 8);
    unsigned short* AsW1 = As + sra * 64 + (((ca0 + 1) ^ (sra & 7)) * 8);

    const int rb0 = t >> 3;
    const int cb  = t & 7;
    const unsigned short* Bb = et + (size_t)i * N2 + (size_t)rb0 * N + cb * 8;
    unsigned short* BsW = Bs + rb0 * 64 + ((cb ^ (rb0 & 7)) * 8);

    f32x4 acc[4][6];
#pragma unroll
    for (int m = 0; m < 4; ++m)
#pragma unroll
        for (int n = 0; n < 6; ++n) acc[m][n] = (f32x4){0.f, 0.f, 0.f, 0.f};

    uint4 va[2], vb[6];
#pragma unroll
    for (int q = 0; q < 2; ++q) va[q] = *(const uint4*)(Ab + q * 8);
#pragma unroll
    for (int it = 0; it < 6; ++it) vb[it] = *(const uint4*)(Bb + (size_t)it * 64 * N);

    for (int k0 = 0; k0 < kmax; k0 += BK) {
        __syncthreads();
        *(uint4*)AsW0 = va[0];
        *(uint4*)AsW1 = va[1];
#pragma unroll
        for (int it = 0; it < 6; ++it) *(uint4*)(BsW + it * 64 * 64) = vb[it];
        __syncthreads();
        if (k0 + BK < kmax) {
            const int kn = k0 + BK;
#pragma unroll
            for (int q = 0; q < 2; ++q) va[q] = *(const uint4*)(Ab + kn + q * 8);
#pragma unroll
            for (int it = 0; it < 6; ++it)
                vb[it] = *(const uint4*)(Bb + (size_t)it * 64 * N + kn);
        }
#pragma unroll
        for (int kk = 0; kk < 2; ++kk) {
            s16x8 af[4], bf[6];
#pragma unroll
            for (int m = 0; m < 4; ++m) {
                const int row = wr + m * 16 + fr;
                const int x   = (kk * 4 + fx) ^ (row & 7);
                af[m] = *(const s16x8*)(As + row * 64 + x * 8);
            }
#pragma unroll
            for (int n = 0; n < 6; ++n) {
                const int row = wc + n * 16 + fr;
                const int x   = (kk * 4 + fx) ^ (row & 7);
                bf[n] = *(const s16x8*)(Bs + row * 64 + x * 8);
            }
#pragma unroll
            for (int m = 0; m < 4; ++m)
#pragma unroll
                for (int n = 0; n < 6; ++n)
                    acc[m][n] = __builtin_amdgcn_mfma_f32_16x16x32_bf16(
                        af[m], bf[n], acc[m][n], 0, 0, 0);
        }
    }

    // Epilogue: 4 phases of 32 fp32 rows in LDS, stream out float4.
    const int rq = fx * 4;
    float* Cf = (float*)smem;    // [32][396]
#pragma unroll
    for (int p = 0; p < 4; ++p) {
        __syncthreads();
        if ((wv >> 2) == (p >> 1)) {
            const int mbase = (p & 1) * 2;
#pragma unroll
            for (int mm = 0; mm < 2; ++mm)
#pragma unroll
                for (int n = 0; n < 6; ++n)
#pragma unroll
                    for (int r = 0; r < 4; ++r)
                        Cf[(mm * 16 + rq + r) * 396 + wc + n * 16 + fr] =
                            acc[mbase + mm][n][r];
        }
        __syncthreads();
#pragma unroll
        for (int it = 0; it < 6; ++it) {
            const int cid = it * 512 + t;
            const int row = cid / 96;
            const int c   = cid % 96;
            float4 v = *(const float4*)(Cf + row * 396 + c * 4);
            *(float4*)(out + (size_t)i * N2 + (size_t)(j0 + p * 32 + row) * N + c * 4) = v;
        }
    }
}

extern "C" void kernel_launch(void* const* d_in, const int* in_sizes, int n_in,
                              void* d_out, int out_size, void* d_ws, size_t ws_size,
                              hipStream_t stream) {
    const float* in = (const float*)d_in[0];
    const float* w  = (const float*)d_in[1];
    float* out      = (float*)d_out;

    unsigned short* r0 = (unsigned short*)d_ws;       // wt -> et
    unsigned short* r1 = (unsigned short*)d_ws + N3;  // e  -> attn

    kT<<<dim3(N2 / 64, N / 64), 256, 0, stream>>>(w, r0);
    k_e2<<<dim3(1152), 512, 0, stream>>>(in, r0, r1);
    k_eT<<<dim3(6, 6, N), 256, 0, stream>>>(r1, r0);
    k_attn<<<dim3(N2 / 4), 256, 0, stream>>>(in, w, r1);
    k_av2<<<dim3(1152), 512, 0, stream>>>(r1, r0, out);
}

// Round 4
// 435.399 us; speedup vs baseline: 2.3840x; 1.5165x over previous
//
#include <hip/hip_runtime.h>
#include <hip/hip_bf16.h>

// Model_39676907885326: out = softmax(causal(q)) @ e
//   e[i,j,l]  = sum_k in[i,j,k] * w[l,k,j]
//   attn[i,j,l] = softmax_{l<=j}( (sum_k in[i,j,k]) * w[i,j,l] / (0.5 + sum_l w[i,j,l]) )
//   out[i]    = attn[i] @ e[i]
//
// Pipeline (ws = 2 regions of N^3 bf16):
//   kT    : w -> wt[j][l][k]          (R0)
//   k_e2  : in, wt -> e[i][j][l]      (R1)  [MFMA 64x192 tile, gll B-staging]
//   k_eT  : e -> et[i][l][m]          (R0)
//   k_attn: in, w -> attn             (R1)
//   k_av2 : attn, et -> out                 [MFMA, triangular, gll A+B staging]

#define N 384
#define N2 (N * N)
#define BK 64
static const size_t N3 = (size_t)N * N * N;

typedef __attribute__((ext_vector_type(8))) short s16x8;
typedef __attribute__((ext_vector_type(4))) float f32x4;

#define AS1 __attribute__((address_space(1)))
#define AS3 __attribute__((address_space(3)))
__device__ __forceinline__ void gll16(const void* g, void* l) {
    __builtin_amdgcn_global_load_lds((const AS1 unsigned int*)g,
                                     (AS3 unsigned int*)l, 16, 0, 0);
}

__device__ __forceinline__ unsigned short f32_to_bf16(float f) {
    unsigned int u = __float_as_uint(f);
    u += 0x7FFFu + ((u >> 16) & 1u);
    return (unsigned short)(u >> 16);
}
__device__ __forceinline__ float bf16_to_f32(unsigned short h) {
    return __uint_as_float((unsigned int)h << 16);
}
__device__ __forceinline__ unsigned int pk2(float a, float b) {
    return (unsigned int)f32_to_bf16(a) | ((unsigned int)f32_to_bf16(b) << 16);
}

// ---------------------------------------------------------------------------
// kT: wt[j*N2 + r] = bf16(w[r*N + j]), r = l*N+k
// ---------------------------------------------------------------------------
__global__ __launch_bounds__(256) void kT(const float* __restrict__ w,
                                          unsigned short* __restrict__ wt) {
    __shared__ unsigned short tile[64][68];
    const int r0 = blockIdx.x * 64;
    const int j0 = blockIdx.y * 64;
    const int tx = threadIdx.x & 63;
    const int ty = threadIdx.x >> 6;
#pragma unroll
    for (int p = 0; p < 16; ++p) {
        const int r = ty * 16 + p;
        tile[r][tx] = f32_to_bf16(w[(size_t)(r0 + r) * N + j0 + tx]);
    }
    __syncthreads();
#pragma unroll
    for (int p = 0; p < 16; ++p) {
        const int jj = ty * 16 + p;
        wt[(size_t)(j0 + jj) * N2 + r0 + tx] = tile[tx][jj];
    }
}

// ---------------------------------------------------------------------------
// k_e2: per j: e[i0..i0+63, j, l0..l0+191] = in[i,j,:] . wt[j][l][:]
// 256 threads (4 waves, 1M x 4N), BM=64, BN=192, BK=64.
// A: register prefetch + cvt + swizzled ds_write. B: global_load_lds with
// pre-swizzled global source (linear LDS dest), XOR-swizzled reads.
// ---------------------------------------------------------------------------
__global__ __launch_bounds__(256, 4) void k_e2(const float* __restrict__ in,
                                               const unsigned short* __restrict__ wt,
                                               unsigned short* __restrict__ e) {
    __shared__ union {
        struct { unsigned short A[64 * 64]; unsigned short B[192 * 64]; } s;
        unsigned short C[64 * 200];
    } sm;

    const int lin = blockIdx.x;               // 4608 = 8 * 576
    const int swz = (lin & 7) * 576 + (lin >> 3);
    const int j   = swz / 12;
    const int sub = swz % 12;
    const int i0  = (sub >> 1) * 64;
    const int l0  = (sub & 1) * 192;

    const int t = threadIdx.x, lane = t & 63, wv = t >> 6;
    const int fr = lane & 15, fx = lane >> 4;

    // A staging (register path): thread -> row ra, chunks ca, ca+1
    const int ra = t >> 2, ca = (t & 3) * 2;
    const float* Ab = in + (size_t)(i0 + ra) * N2 + (size_t)j * N + ca * 8;
    unsigned short* AsW0 = sm.s.A + ra * 64 + (((ca + 0) ^ (ra & 7)) * 8);
    unsigned short* AsW1 = sm.s.A + ra * 64 + (((ca + 1) ^ (ra & 7)) * 8);

    // B staging via gll: wave rows [wv*48, wv*48+48), 6 ops x 8 rows
    const unsigned short* Wj = wt + (size_t)j * N2 + (size_t)l0 * N;
    const int rb_off = lane >> 3;             // 0..7 within op
    const int p8     = lane & 7;              // LDS chunk pos

    f32x4 acc[4][3];
#pragma unroll
    for (int m = 0; m < 4; ++m)
#pragma unroll
        for (int n = 0; n < 3; ++n) acc[m][n] = (f32x4){0.f, 0.f, 0.f, 0.f};

    float4 va[4];
    va[0] = *(const float4*)(Ab);
    va[1] = *(const float4*)(Ab + 4);
    va[2] = *(const float4*)(Ab + 8);
    va[3] = *(const float4*)(Ab + 12);

    for (int k0 = 0; k0 < N; k0 += BK) {
        __syncthreads();
        {
            uint4 a0, a1;
            a0.x = pk2(va[0].x, va[0].y); a0.y = pk2(va[0].z, va[0].w);
            a0.z = pk2(va[1].x, va[1].y); a0.w = pk2(va[1].z, va[1].w);
            a1.x = pk2(va[2].x, va[2].y); a1.y = pk2(va[2].z, va[2].w);
            a1.z = pk2(va[3].x, va[3].y); a1.w = pk2(va[3].z, va[3].w);
            *(uint4*)AsW0 = a0;
            *(uint4*)AsW1 = a1;
        }
#pragma unroll
        for (int itb = 0; itb < 6; ++itb) {
            const int rb = wv * 48 + itb * 8 + rb_off;
            const int sc = p8 ^ (rb & 7);
            gll16(Wj + (size_t)rb * N + k0 + sc * 8,
                  sm.s.B + (wv * 48 + itb * 8) * 64);
        }
        if (k0 + BK < N) {
            const float* An = Ab + k0 + BK;
            va[0] = *(const float4*)(An);
            va[1] = *(const float4*)(An + 4);
            va[2] = *(const float4*)(An + 8);
            va[3] = *(const float4*)(An + 12);
        }
        __syncthreads();
#pragma unroll
        for (int kk = 0; kk < 2; ++kk) {
            s16x8 af[4], bf[3];
#pragma unroll
            for (int m = 0; m < 4; ++m) {
                const int row = m * 16 + fr;
                const int x   = (kk * 4 + fx) ^ (row & 7);
                af[m] = *(const s16x8*)(sm.s.A + row * 64 + x * 8);
            }
#pragma unroll
            for (int n = 0; n < 3; ++n) {
                const int row = wv * 48 + n * 16 + fr;
                const int x   = (kk * 4 + fx) ^ (row & 7);
                bf[n] = *(const s16x8*)(sm.s.B + row * 64 + x * 8);
            }
#pragma unroll
            for (int m = 0; m < 4; ++m)
#pragma unroll
                for (int n = 0; n < 3; ++n)
                    acc[m][n] = __builtin_amdgcn_mfma_f32_16x16x32_bf16(
                        af[m], bf[n], acc[m][n], 0, 0, 0);
        }
    }

    // epilogue: assemble 64x192 bf16 in LDS, stream full lines
    __syncthreads();
#pragma unroll
    for (int m = 0; m < 4; ++m)
#pragma unroll
        for (int n = 0; n < 3; ++n)
#pragma unroll
            for (int r = 0; r < 4; ++r)
                sm.C[(m * 16 + fx * 4 + r) * 200 + wv * 48 + n * 16 + fr] =
                    f32_to_bf16(acc[m][n][r]);
    __syncthreads();
#pragma unroll
    for (int it = 0; it < 6; ++it) {
        const int cid = it * 256 + t;
        const int row = cid / 24;
        const int c   = cid % 24;
        *(uint4*)(e + (size_t)(i0 + row) * N2 + (size_t)j * N + l0 + c * 8) =
            *(const uint4*)&sm.C[row * 200 + c * 8];
    }
}

// ---------------------------------------------------------------------------
// k_eT: et[i][l][m] = e[i][m][l]
// ---------------------------------------------------------------------------
__global__ __launch_bounds__(256) void k_eT(const unsigned short* __restrict__ e,
                                            unsigned short* __restrict__ et) {
    __shared__ unsigned short tile[64][68];
    const int m0 = blockIdx.x * 64, l0 = blockIdx.y * 64;
    const size_t ib = (size_t)blockIdx.z * N2;
    const int t  = threadIdx.x;
    const int c4 = (t & 15) * 4, r = t >> 4;
#pragma unroll
    for (int p = 0; p < 4; ++p) {
        ushort4 v = *(const ushort4*)(e + ib + (size_t)(m0 + r + 16 * p) * N + l0 + c4);
        tile[c4 + 0][r + 16 * p] = v.x;
        tile[c4 + 1][r + 16 * p] = v.y;
        tile[c4 + 2][r + 16 * p] = v.z;
        tile[c4 + 3][r + 16 * p] = v.w;
    }
    __syncthreads();
#pragma unroll
    for (int p = 0; p < 4; ++p) {
        const int lr = r + 16 * p;
        ushort4 v = *(const ushort4*)&tile[lr][c4];
        *(ushort4*)(et + ib + (size_t)(l0 + lr) * N + m0 + c4) = v;
    }
}

// ---------------------------------------------------------------------------
// k_attn: one wave per row (i,j), float2-vectorized
// ---------------------------------------------------------------------------
__global__ __launch_bounds__(256) void k_attn(const float* __restrict__ in,
                                              const float* __restrict__ w,
                                              unsigned short* __restrict__ attn) {
    const int row  = blockIdx.x * 4 + (threadIdx.x >> 6);
    const int lane = threadIdx.x & 63;
    const int jr   = row % N;

    const float2* ip = (const float2*)(in + (size_t)row * N);
    const float2* wp = (const float2*)(w + (size_t)row * N);

    float2 wv[3];
    float rs_in = 0.f, rs_w = 0.f;
#pragma unroll
    for (int c = 0; c < 3; ++c) {
        float2 iv = ip[lane + 64 * c];
        wv[c] = wp[lane + 64 * c];
        rs_in += iv.x + iv.y;
        rs_w  += wv[c].x + wv[c].y;
    }
#pragma unroll
    for (int s = 1; s < 64; s <<= 1) {
        rs_in += __shfl_xor(rs_in, s, 64);
        rs_w  += __shfl_xor(rs_w, s, 64);
    }
    const float scale = rs_in / (0.5f + rs_w);

    float2 q[3];
    float mx = -INFINITY;
#pragma unroll
    for (int c = 0; c < 3; ++c) {
        const int l = (lane + 64 * c) * 2;
        q[c].x = (l     <= jr) ? scale * wv[c].x : -INFINITY;
        q[c].y = (l + 1 <= jr) ? scale * wv[c].y : -INFINITY;
        mx = fmaxf(mx, fmaxf(q[c].x, q[c].y));
    }
#pragma unroll
    for (int s = 1; s < 64; s <<= 1) mx = fmaxf(mx, __shfl_xor(mx, s, 64));

    float2 p[3];
    float sum = 0.f;
#pragma unroll
    for (int c = 0; c < 3; ++c) {
        const int l = (lane + 64 * c) * 2;
        p[c].x = (l     <= jr) ? exp2f((q[c].x - mx) * 1.44269504f) : 0.f;
        p[c].y = (l + 1 <= jr) ? exp2f((q[c].y - mx) * 1.44269504f) : 0.f;
        sum += p[c].x + p[c].y;
    }
#pragma unroll
    for (int s = 1; s < 64; s <<= 1) sum += __shfl_xor(sum, s, 64);
    const float inv = 1.f / sum;
    unsigned int* ap = (unsigned int*)(attn + (size_t)row * N);
#pragma unroll
    for (int c = 0; c < 3; ++c)
        ap[lane + 64 * c] = pk2(p[c].x * inv, p[c].y * inv);
}

// ---------------------------------------------------------------------------
// k_av2: per i: out[j0..j0+63, l0..l0+191] = attn[i] @ et[i]^T, K <= j0+64
// A and B both staged via gll (pre-swizzled source, linear LDS).
// ---------------------------------------------------------------------------
__global__ __launch_bounds__(256, 4) void k_av2(const unsigned short* __restrict__ attn,
                                                const unsigned short* __restrict__ et,
                                                float* __restrict__ out) {
    __shared__ union {
        struct { unsigned short A[64 * 64]; unsigned short B[192 * 64]; } s;
        float C[32 * 196];
    } sm;

    const int lin = blockIdx.x;               // 4608 = 8 * 576
    const int swz = (lin & 7) * 576 + (lin >> 3);
    const int i   = swz / 12;
    const int sub = swz % 12;
    const int j0  = (sub >> 1) * 64;
    const int l0  = (sub & 1) * 192;
    const int kmax = j0 + 64;

    const int t = threadIdx.x, lane = t & 63, wv = t >> 6;
    const int fr = lane & 15, fx = lane >> 4;
    const int rb_off = lane >> 3;
    const int p8     = lane & 7;

    const unsigned short* Ag = attn + (size_t)i * N2 + (size_t)j0 * N;
    const unsigned short* Bg = et + (size_t)i * N2 + (size_t)l0 * N;

    f32x4 acc[4][3];
#pragma unroll
    for (int m = 0; m < 4; ++m)
#pragma unroll
        for (int n = 0; n < 3; ++n) acc[m][n] = (f32x4){0.f, 0.f, 0.f, 0.f};

    for (int k0 = 0; k0 < kmax; k0 += BK) {
        __syncthreads();
        // A: 64 rows, wave covers [wv*16, wv*16+16), 2 ops x 8 rows
#pragma unroll
        for (int ita = 0; ita < 2; ++ita) {
            const int rb = wv * 16 + ita * 8 + rb_off;
            const int sc = p8 ^ (rb & 7);
            gll16(Ag + (size_t)rb * N + k0 + sc * 8,
                  sm.s.A + (wv * 16 + ita * 8) * 64);
        }
        // B: 192 rows, wave covers [wv*48, wv*48+48), 6 ops x 8 rows
#pragma unroll
        for (int itb = 0; itb < 6; ++itb) {
            const int rb = wv * 48 + itb * 8 + rb_off;
            const int sc = p8 ^ (rb & 7);
            gll16(Bg + (size_t)rb * N + k0 + sc * 8,
                  sm.s.B + (wv * 48 + itb * 8) * 64);
        }
        __syncthreads();
#pragma unroll
        for (int kk = 0; kk < 2; ++kk) {
            s16x8 af[4], bf[3];
#pragma unroll
            for (int m = 0; m < 4; ++m) {
                const int row = m * 16 + fr;
                const int x   = (kk * 4 + fx) ^ (row & 7);
                af[m] = *(const s16x8*)(sm.s.A + row * 64 + x * 8);
            }
#pragma unroll
            for (int n = 0; n < 3; ++n) {
                const int row = wv * 48 + n * 16 + fr;
                const int x   = (kk * 4 + fx) ^ (row & 7);
                bf[n] = *(const s16x8*)(sm.s.B + row * 64 + x * 8);
            }
#pragma unroll
            for (int m = 0; m < 4; ++m)
#pragma unroll
                for (int n = 0; n < 3; ++n)
                    acc[m][n] = __builtin_amdgcn_mfma_f32_16x16x32_bf16(
                        af[m], bf[n], acc[m][n], 0, 0, 0);
        }
    }

    // epilogue: 2 phases of 32 fp32 rows
#pragma unroll
    for (int ph = 0; ph < 2; ++ph) {
        __syncthreads();
#pragma unroll
        for (int mm = 0; mm < 2; ++mm)
#pragma unroll
            for (int n = 0; n < 3; ++n)
#pragma unroll
                for (int r = 0; r < 4; ++r)
                    sm.C[(mm * 16 + fx * 4 + r) * 196 + wv * 48 + n * 16 + fr] =
                        acc[ph * 2 + mm][n][r];
        __syncthreads();
#pragma unroll
        for (int it = 0; it < 6; ++it) {
            const int cid = it * 256 + t;
            const int row = cid / 48;
            const int c   = cid % 48;
            *(float4*)(out + (size_t)i * N2 + (size_t)(j0 + ph * 32 + row) * N + l0 + c * 4) =
                *(const float4*)&sm.C[row * 196 + c * 4];
        }
    }
}

extern "C" void kernel_launch(void* const* d_in, const int* in_sizes, int n_in,
                              void* d_out, int out_size, void* d_ws, size_t ws_size,
                              hipStream_t stream) {
    const float* in = (const float*)d_in[0];
    const float* w  = (const float*)d_in[1];
    float* out      = (float*)d_out;

    unsigned short* r0 = (unsigned short*)d_ws;       // wt -> et
    unsigned short* r1 = (unsigned short*)d_ws + N3;  // e  -> attn

    kT<<<dim3(N2 / 64, N / 64), 256, 0, stream>>>(w, r0);
    k_e2<<<dim3(4608), 256, 0, stream>>>(in, r0, r1);
    k_eT<<<dim3(6, 6, N), 256, 0, stream>>>(r1, r0);
    k_attn<<<dim3(N2 / 4), 256, 0, stream>>>(in, w, r1);
    k_av2<<<dim3(4608), 256, 0, stream>>>(r1, r0, out);
}

// Round 5
// 398.472 us; speedup vs baseline: 2.6050x; 1.0927x over previous
//
#include <hip/hip_runtime.h>
#include <hip/hip_bf16.h>

// Model_39676907885326: out = softmax(causal(q)) @ e
//   e[i,j,l]  = sum_k in[i,j,k] * w[l,k,j]
//   attn[i,j,l] = softmax_{l<=j}( (sum_k in[i,j,k]) * w[i,j,l] / (0.5 + sum_l w[i,j,l]) )
//   out[i]    = attn[i] @ e[i]
//
// Pipeline (ws regions):
//   R0 [0, N3) bf16        : wt[j][l][k]  ->  et[i][l][m]
//   R1 [N3, 2*N3) bf16     : e[i][j][l]   ->  attn[i][j][m]
//   RS [2*N3 ..) fp32 N2   : rs[i][j] = sum_k in[i,j,k]   (written by k_e2)
//   kT -> k_e2(+rs) -> k_eT -> k_attn(rs) -> k_av2

#define N 384
#define N2 (N * N)
#define BK 64
static const size_t N3 = (size_t)N * N * N;

typedef __attribute__((ext_vector_type(8))) short s16x8;
typedef __attribute__((ext_vector_type(4))) float f32x4;

#define AS1 __attribute__((address_space(1)))
#define AS3 __attribute__((address_space(3)))
__device__ __forceinline__ void gll16(const void* g, void* l) {
    __builtin_amdgcn_global_load_lds((const AS1 unsigned int*)g,
                                     (AS3 unsigned int*)l, 16, 0, 0);
}

__device__ __forceinline__ unsigned short f32_to_bf16(float f) {
    unsigned int u = __float_as_uint(f);
    u += 0x7FFFu + ((u >> 16) & 1u);
    return (unsigned short)(u >> 16);
}
__device__ __forceinline__ float bf16_to_f32(unsigned short h) {
    return __uint_as_float((unsigned int)h << 16);
}
__device__ __forceinline__ unsigned int pk2(float a, float b) {
    return (unsigned int)f32_to_bf16(a) | ((unsigned int)f32_to_bf16(b) << 16);
}

// ---------------------------------------------------------------------------
// kT: wt[j*N2 + r] = bf16(w[r*N + j]), r = l*N+k
// ---------------------------------------------------------------------------
__global__ __launch_bounds__(256) void kT(const float* __restrict__ w,
                                          unsigned short* __restrict__ wt) {
    __shared__ unsigned short tile[64][68];
    const int r0 = blockIdx.x * 64;
    const int j0 = blockIdx.y * 64;
    const int tx = threadIdx.x & 63;
    const int ty = threadIdx.x >> 6;
#pragma unroll
    for (int p = 0; p < 16; ++p) {
        const int r = ty * 16 + p;
        tile[r][tx] = f32_to_bf16(w[(size_t)(r0 + r) * N + j0 + tx]);
    }
    __syncthreads();
#pragma unroll
    for (int p = 0; p < 16; ++p) {
        const int jj = ty * 16 + p;
        wt[(size_t)(j0 + jj) * N2 + r0 + tx] = tile[tx][jj];
    }
}

// ---------------------------------------------------------------------------
// k_e2: per j: e[i0..i0+63, j, l0..l0+191] = in[i,j,:] . wt[j][l][:]
// 256 threads (4 waves). A: register prefetch + cvt + swizzled ds_write,
// with fused row-sum rs[i,j]. B: global_load_lds, pre-swizzled source.
// ---------------------------------------------------------------------------
__global__ __launch_bounds__(256, 4) void k_e2(const float* __restrict__ in,
                                               const unsigned short* __restrict__ wt,
                                               unsigned short* __restrict__ e,
                                               float* __restrict__ rs) {
    __shared__ union {
        struct { unsigned short A[64 * 64]; unsigned short B[192 * 64]; } s;
        unsigned short C[64 * 200];
    } sm;

    const int lin = blockIdx.x;               // 4608 = 8 * 576
    const int swz = (lin & 7) * 576 + (lin >> 3);
    const int j   = swz / 12;
    const int sub = swz % 12;
    const int i0  = (sub >> 1) * 64;
    const int l0  = (sub & 1) * 192;

    const int t = threadIdx.x, lane = t & 63, wv = t >> 6;
    const int fr = lane & 15, fx = lane >> 4;

    const int ra = t >> 2, ca = (t & 3) * 2;
    const float* Ab = in + (size_t)(i0 + ra) * N2 + (size_t)j * N + ca * 8;
    unsigned short* AsW0 = sm.s.A + ra * 64 + (((ca + 0) ^ (ra & 7)) * 8);
    unsigned short* AsW1 = sm.s.A + ra * 64 + (((ca + 1) ^ (ra & 7)) * 8);

    const unsigned short* Wj = wt + (size_t)j * N2 + (size_t)l0 * N;
    const int rb_off = lane >> 3;
    const int p8     = lane & 7;

    f32x4 acc[4][3];
#pragma unroll
    for (int m = 0; m < 4; ++m)
#pragma unroll
        for (int n = 0; n < 3; ++n) acc[m][n] = (f32x4){0.f, 0.f, 0.f, 0.f};

    float rsum = 0.f;   // this thread's share of sum_k in[i0+ra, j, k]

    float4 va[4];
    va[0] = *(const float4*)(Ab);
    va[1] = *(const float4*)(Ab + 4);
    va[2] = *(const float4*)(Ab + 8);
    va[3] = *(const float4*)(Ab + 12);

    for (int k0 = 0; k0 < N; k0 += BK) {
        __syncthreads();
        {
            rsum += (va[0].x + va[0].y + va[0].z + va[0].w) +
                    (va[1].x + va[1].y + va[1].z + va[1].w) +
                    (va[2].x + va[2].y + va[2].z + va[2].w) +
                    (va[3].x + va[3].y + va[3].z + va[3].w);
            uint4 a0, a1;
            a0.x = pk2(va[0].x, va[0].y); a0.y = pk2(va[0].z, va[0].w);
            a0.z = pk2(va[1].x, va[1].y); a0.w = pk2(va[1].z, va[1].w);
            a1.x = pk2(va[2].x, va[2].y); a1.y = pk2(va[2].z, va[2].w);
            a1.z = pk2(va[3].x, va[3].y); a1.w = pk2(va[3].z, va[3].w);
            *(uint4*)AsW0 = a0;
            *(uint4*)AsW1 = a1;
        }
#pragma unroll
        for (int itb = 0; itb < 6; ++itb) {
            const int rb = wv * 48 + itb * 8 + rb_off;
            const int sc = p8 ^ (rb & 7);
            gll16(Wj + (size_t)rb * N + k0 + sc * 8,
                  sm.s.B + (wv * 48 + itb * 8) * 64);
        }
        if (k0 + BK < N) {
            const float* An = Ab + k0 + BK;
            va[0] = *(const float4*)(An);
            va[1] = *(const float4*)(An + 4);
            va[2] = *(const float4*)(An + 8);
            va[3] = *(const float4*)(An + 12);
        }
        __syncthreads();
#pragma unroll
        for (int kk = 0; kk < 2; ++kk) {
            s16x8 af[4], bf[3];
#pragma unroll
            for (int m = 0; m < 4; ++m) {
                const int row = m * 16 + fr;
                const int x   = (kk * 4 + fx) ^ (row & 7);
                af[m] = *(const s16x8*)(sm.s.A + row * 64 + x * 8);
            }
#pragma unroll
            for (int n = 0; n < 3; ++n) {
                const int row = wv * 48 + n * 16 + fr;
                const int x   = (kk * 4 + fx) ^ (row & 7);
                bf[n] = *(const s16x8*)(sm.s.B + row * 64 + x * 8);
            }
#pragma unroll
            for (int m = 0; m < 4; ++m)
#pragma unroll
                for (int n = 0; n < 3; ++n)
                    acc[m][n] = __builtin_amdgcn_mfma_f32_16x16x32_bf16(
                        af[m], bf[n], acc[m][n], 0, 0, 0);
        }
    }

    // fused row-sum: reduce the 4 threads sharing row ra, l0==0 blocks write
    rsum += __shfl_xor(rsum, 1, 64);
    rsum += __shfl_xor(rsum, 2, 64);
    if (rs != nullptr && l0 == 0 && (t & 3) == 0)
        rs[(size_t)(i0 + ra) * N + j] = rsum;

    // epilogue: assemble 64x192 bf16 in LDS, stream full lines
    __syncthreads();
#pragma unroll
    for (int m = 0; m < 4; ++m)
#pragma unroll
        for (int n = 0; n < 3; ++n)
#pragma unroll
            for (int r = 0; r < 4; ++r)
                sm.C[(m * 16 + fx * 4 + r) * 200 + wv * 48 + n * 16 + fr] =
                    f32_to_bf16(acc[m][n][r]);
    __syncthreads();
#pragma unroll
    for (int it = 0; it < 6; ++it) {
        const int cid = it * 256 + t;
        const int row = cid / 24;
        const int c   = cid % 24;
        *(uint4*)(e + (size_t)(i0 + row) * N2 + (size_t)j * N + l0 + c * 8) =
            *(const uint4*)&sm.C[row * 200 + c * 8];
    }
}

// ---------------------------------------------------------------------------
// k_eT: et[i][l][m] = e[i][m][l]
// ---------------------------------------------------------------------------
__global__ __launch_bounds__(256) void k_eT(const unsigned short* __restrict__ e,
                                            unsigned short* __restrict__ et) {
    __shared__ unsigned short tile[64][68];
    const int m0 = blockIdx.x * 64, l0 = blockIdx.y * 64;
    const size_t ib = (size_t)blockIdx.z * N2;
    const int t  = threadIdx.x;
    const int c4 = (t & 15) * 4, r = t >> 4;
#pragma unroll
    for (int p = 0; p < 4; ++p) {
        ushort4 v = *(const ushort4*)(e + ib + (size_t)(m0 + r + 16 * p) * N + l0 + c4);
        tile[c4 + 0][r + 16 * p] = v.x;
        tile[c4 + 1][r + 16 * p] = v.y;
        tile[c4 + 2][r + 16 * p] = v.z;
        tile[c4 + 3][r + 16 * p] = v.w;
    }
    __syncthreads();
#pragma unroll
    for (int p = 0; p < 4; ++p) {
        const int lr = r + 16 * p;
        ushort4 v = *(const ushort4*)&tile[lr][c4];
        *(ushort4*)(et + ib + (size_t)(l0 + lr) * N + m0 + c4) = v;
    }
}

// ---------------------------------------------------------------------------
// k_attn: one wave per row (i,j); rs precomputed by k_e2 (rs != nullptr)
// or computed from in (fallback).
// ---------------------------------------------------------------------------
template <bool HAVE_RS>
__global__ __launch_bounds__(256) void k_attn(const float* __restrict__ in,
                                              const float* __restrict__ w,
                                              const float* __restrict__ rs,
                                              unsigned short* __restrict__ attn) {
    const int row  = blockIdx.x * 4 + (threadIdx.x >> 6);
    const int lane = threadIdx.x & 63;
    const int jr   = row % N;

    const float2* wp = (const float2*)(w + (size_t)row * N);

    float2 wv[3];
    float rs_in = 0.f, rs_w = 0.f;
#pragma unroll
    for (int c = 0; c < 3; ++c) {
        wv[c] = wp[lane + 64 * c];
        rs_w += wv[c].x + wv[c].y;
    }
    if (HAVE_RS) {
#pragma unroll
        for (int s = 1; s < 64; s <<= 1) rs_w += __shfl_xor(rs_w, s, 64);
        rs_in = rs[row];
    } else {
        const float2* ip = (const float2*)(in + (size_t)row * N);
#pragma unroll
        for (int c = 0; c < 3; ++c) {
            float2 iv = ip[lane + 64 * c];
            rs_in += iv.x + iv.y;
        }
#pragma unroll
        for (int s = 1; s < 64; s <<= 1) {
            rs_in += __shfl_xor(rs_in, s, 64);
            rs_w  += __shfl_xor(rs_w, s, 64);
        }
    }
    const float scale = rs_in / (0.5f + rs_w);

    float2 q[3];
    float mx = -INFINITY;
#pragma unroll
    for (int c = 0; c < 3; ++c) {
        const int l = (lane + 64 * c) * 2;
        q[c].x = (l     <= jr) ? scale * wv[c].x : -INFINITY;
        q[c].y = (l + 1 <= jr) ? scale * wv[c].y : -INFINITY;
        mx = fmaxf(mx, fmaxf(q[c].x, q[c].y));
    }
#pragma unroll
    for (int s = 1; s < 64; s <<= 1) mx = fmaxf(mx, __shfl_xor(mx, s, 64));

    float2 p[3];
    float sum = 0.f;
#pragma unroll
    for (int c = 0; c < 3; ++c) {
        const int l = (lane + 64 * c) * 2;
        p[c].x = (l     <= jr) ? exp2f((q[c].x - mx) * 1.44269504f) : 0.f;
        p[c].y = (l + 1 <= jr) ? exp2f((q[c].y - mx) * 1.44269504f) : 0.f;
        sum += p[c].x + p[c].y;
    }
#pragma unroll
    for (int s = 1; s < 64; s <<= 1) sum += __shfl_xor(sum, s, 64);
    const float inv = 1.f / sum;
    unsigned int* ap = (unsigned int*)(attn + (size_t)row * N);
#pragma unroll
    for (int c = 0; c < 3; ++c)
        ap[lane + 64 * c] = pk2(p[c].x * inv, p[c].y * inv);
}

// ---------------------------------------------------------------------------
// k_av2: per i: out[j0..j0+63, l0..l0+191] = attn[i] @ et[i]^T, K <= j0+64
// ---------------------------------------------------------------------------
__global__ __launch_bounds__(256, 4) void k_av2(const unsigned short* __restrict__ attn,
                                                const unsigned short* __restrict__ et,
                                                float* __restrict__ out) {
    __shared__ union {
        struct { unsigned short A[64 * 64]; unsigned short B[192 * 64]; } s;
        float C[32 * 196];
    } sm;

    const int lin = blockIdx.x;
    const int swz = (lin & 7) * 576 + (lin >> 3);
    const int i   = swz / 12;
    const int sub = swz % 12;
    const int j0  = (sub >> 1) * 64;
    const int l0  = (sub & 1) * 192;
    const int kmax = j0 + 64;

    const int t = threadIdx.x, lane = t & 63, wv = t >> 6;
    const int fr = lane & 15, fx = lane >> 4;
    const int rb_off = lane >> 3;
    const int p8     = lane & 7;

    const unsigned short* Ag = attn + (size_t)i * N2 + (size_t)j0 * N;
    const unsigned short* Bg = et + (size_t)i * N2 + (size_t)l0 * N;

    f32x4 acc[4][3];
#pragma unroll
    for (int m = 0; m < 4; ++m)
#pragma unroll
        for (int n = 0; n < 3; ++n) acc[m][n] = (f32x4){0.f, 0.f, 0.f, 0.f};

    for (int k0 = 0; k0 < kmax; k0 += BK) {
        __syncthreads();
#pragma unroll
        for (int ita = 0; ita < 2; ++ita) {
            const int rb = wv * 16 + ita * 8 + rb_off;
            const int sc = p8 ^ (rb & 7);
            gll16(Ag + (size_t)rb * N + k0 + sc * 8,
                  sm.s.A + (wv * 16 + ita * 8) * 64);
        }
#pragma unroll
        for (int itb = 0; itb < 6; ++itb) {
            const int rb = wv * 48 + itb * 8 + rb_off;
            const int sc = p8 ^ (rb & 7);
            gll16(Bg + (size_t)rb * N + k0 + sc * 8,
                  sm.s.B + (wv * 48 + itb * 8) * 64);
        }
        __syncthreads();
#pragma unroll
        for (int kk = 0; kk < 2; ++kk) {
            s16x8 af[4], bf[3];
#pragma unroll
            for (int m = 0; m < 4; ++m) {
                const int row = m * 16 + fr;
                const int x   = (kk * 4 + fx) ^ (row & 7);
                af[m] = *(const s16x8*)(sm.s.A + row * 64 + x * 8);
            }
#pragma unroll
            for (int n = 0; n < 3; ++n) {
                const int row = wv * 48 + n * 16 + fr;
                const int x   = (kk * 4 + fx) ^ (row & 7);
                bf[n] = *(const s16x8*)(sm.s.B + row * 64 + x * 8);
            }
#pragma unroll
            for (int m = 0; m < 4; ++m)
#pragma unroll
                for (int n = 0; n < 3; ++n)
                    acc[m][n] = __builtin_amdgcn_mfma_f32_16x16x32_bf16(
                        af[m], bf[n], acc[m][n], 0, 0, 0);
        }
    }

#pragma unroll
    for (int ph = 0; ph < 2; ++ph) {
        __syncthreads();
#pragma unroll
        for (int mm = 0; mm < 2; ++mm)
#pragma unroll
            for (int n = 0; n < 3; ++n)
#pragma unroll
                for (int r = 0; r < 4; ++r)
                    sm.C[(mm * 16 + fx * 4 + r) * 196 + wv * 48 + n * 16 + fr] =
                        acc[ph * 2 + mm][n][r];
        __syncthreads();
#pragma unroll
        for (int it = 0; it < 6; ++it) {
            const int cid = it * 256 + t;
            const int row = cid / 48;
            const int c   = cid % 48;
            *(float4*)(out + (size_t)i * N2 + (size_t)(j0 + ph * 32 + row) * N + l0 + c * 4) =
                *(const float4*)&sm.C[row * 196 + c * 4];
        }
    }
}

extern "C" void kernel_launch(void* const* d_in, const int* in_sizes, int n_in,
                              void* d_out, int out_size, void* d_ws, size_t ws_size,
                              hipStream_t stream) {
    const float* in = (const float*)d_in[0];
    const float* w  = (const float*)d_in[1];
    float* out      = (float*)d_out;

    unsigned short* r0 = (unsigned short*)d_ws;       // wt -> et
    unsigned short* r1 = (unsigned short*)d_ws + N3;  // e  -> attn
    const bool have_rs = ws_size >= 2 * N3 * sizeof(unsigned short) + (size_t)N2 * sizeof(float);
    float* rs = have_rs ? (float*)((unsigned short*)d_ws + 2 * N3) : nullptr;

    kT<<<dim3(N2 / 64, N / 64), 256, 0, stream>>>(w, r0);
    k_e2<<<dim3(4608), 256, 0, stream>>>(in, r0, r1, rs);
    k_eT<<<dim3(6, 6, N), 256, 0, stream>>>(r1, r0);
    if (have_rs)
        k_attn<true><<<dim3(N2 / 4), 256, 0, stream>>>(in, w, rs, r1);
    else
        k_attn<false><<<dim3(N2 / 4), 256, 0, stream>>>(in, w, nullptr, r1);
    k_av2<<<dim3(4608), 256, 0, stream>>>(r1, r0, out);
}